// Round 2
// baseline (4936.082 us; speedup 1.0000x reference)
//
#include <hip/hip_runtime.h>
#include <hip/hip_bf16.h>
#include <hip/hip_fp16.h>

// Problem constants
#define IMGS 2
#define CH 3
#define HW 96
#define PATCH 7
#define OW 90                  // output spatial dim (96-7+1)
#define NP 8100                // 90*90 patches per image
#define DIM 147                // 3*7*7
#define IMG_STRIDE 27648       // 3*96*96
#define CH_STRIDE 9216         // 96*96
#define ALPHA 0.05f
#define INV_D (1.0f/147.0f)

// ws layout (float offsets)
#define WS_XR   0              // rounded x images, 2*27648
#define WS_YR   55296          // rounded y images
#define WS_N2X  110592         // x patch sq-norms [img][8100]
#define WS_N2Y  126792         // y patch sq-norms
#define WS_RINV 142992         // 1/(row_min+alpha) per target [img][8100]
#define WS_PART 159192         // per-block partial col-min sums [img*128 + tile]

// ---------------- prep: round inputs through fp16 (reference casts to fp16
// before patch extraction), store as fp32 for fast VALU math ----------------
__global__ __launch_bounds__(256) void k_prep(const float* __restrict__ x,
                                              const float* __restrict__ y,
                                              float* __restrict__ ws) {
    int idx = blockIdx.x * 256 + threadIdx.x;
    if (idx < IMGS * IMG_STRIDE) {
        ws[WS_XR + idx] = __half2float(__float2half(x[idx]));
        ws[WS_YR + idx] = __half2float(__float2half(y[idx]));
    }
}

// ---------------- per-patch squared norms ----------------
__global__ __launch_bounds__(256) void k_norms(float* __restrict__ ws) {
    int idx = blockIdx.x * 256 + threadIdx.x;
    if (idx >= 2 * IMGS * NP) return;
    int tensor = idx / (IMGS * NP);       // 0 = x, 1 = y
    int r = idx % (IMGS * NP);
    int img = r / NP;
    int p = r % NP;
    const float* src = ws + (tensor ? WS_YR : WS_XR) + img * IMG_STRIDE;
    int py = p / OW, px = p - py * OW;
    const float* base = src + py * HW + px;
    float s = 0.0f;
#pragma unroll
    for (int c = 0; c < CH; c++)
#pragma unroll
        for (int dy = 0; dy < PATCH; dy++)
#pragma unroll
            for (int dx = 0; dx < PATCH; dx++) {
                float v = base[c * CH_STRIDE + dy * HW + dx];
                s = fmaf(v, v, s);
            }
    ws[(tensor ? WS_N2Y : WS_N2X) + img * NP + p] = s;
}

// ---------------- pass 1: per-target row min over all inputs -> row_inv ----
// grid = 2 images * 127 target-tiles(64); block = 256 (k = target lane 0..63,
// q = wave id = quarter of the input range)
__global__ __launch_bounds__(256) void k_pass1(float* __restrict__ ws) {
    __shared__ float ylds[64 * 149];   // stride 149 (odd) -> 2-way bank alias, free
    __shared__ float red[256];
    int bx = blockIdx.x;
    int img = bx / 127;
    int tile = bx % 127;
    int t0 = tile * 64;
    int tid = threadIdx.x;
    int k = tid & 63, q = tid >> 6;

    // stage 64 target patches into LDS
    {
        int t = t0 + k;
        bool valid = t < NP;
        int ty = valid ? t / OW : 0;
        int tx = valid ? (t - ty * OW) : 0;
        const float* ybase = ws + WS_YR + img * IMG_STRIDE + ty * HW + tx;
        int e0 = q * 37, e1 = (q * 37 + 37 < DIM) ? q * 37 + 37 : DIM;
        for (int e = e0; e < e1; e++) {
            int c = e / 49;
            int rm = e - c * 49;
            int dy = rm / 7;
            int dx = rm - dy * 7;
            ylds[k * 149 + e] = valid ? ybase[c * CH_STRIDE + dy * HW + dx] : 0.0f;
        }
    }
    __syncthreads();

    int t = t0 + k;
    float y2t = ws[WS_N2Y + img * NP + (t < NP ? t : 0)];
    const float* xim = ws + WS_XR + img * IMG_STRIDE;
    const float* n2x = ws + WS_N2X + img * NP;
    const float* yl = &ylds[k * 149];

    float lmin = 3.4e38f;
    int i0 = q * 2025;                 // 4 * 2025 == 8100 exactly
    int iy = i0 / OW, ix = i0 - (i0 / OW) * OW;
    for (int j = 0; j < 2025; j++) {
        const float* xb = xim + iy * HW + ix;   // wave-uniform -> broadcast loads
        float a0 = 0.f, a1 = 0.f, a2 = 0.f, a3 = 0.f;
#pragma unroll
        for (int c = 0; c < CH; c++) {
#pragma unroll
            for (int dy = 0; dy < PATCH; dy++) {
                const float* xr = xb + c * CH_STRIDE + dy * HW;
                const float* yr = yl + c * 49 + dy * 7;
                a0 = fmaf(yr[0], xr[0], a0);
                a1 = fmaf(yr[1], xr[1], a1);
                a2 = fmaf(yr[2], xr[2], a2);
                a3 = fmaf(yr[3], xr[3], a3);
                a0 = fmaf(yr[4], xr[4], a0);
                a1 = fmaf(yr[5], xr[5], a1);
                a2 = fmaf(yr[6], xr[6], a2);
            }
        }
        float cross = (a0 + a1) + (a2 + a3);
        float d = (y2t + n2x[i0 + j] - 2.0f * cross) * INV_D;
        lmin = fminf(lmin, d);
        ix++; if (ix == OW) { ix = 0; iy++; }
    }
    red[tid] = lmin;
    __syncthreads();
    if (tid < 64) {
        float m = fminf(fminf(red[tid], red[64 + tid]),
                        fminf(red[128 + tid], red[192 + tid]));
        int tt = t0 + tid;
        if (tt < NP) ws[WS_RINV + img * NP + tt] = 1.0f / (m + ALPHA);
    }
}

// ---------------- pass 2: per-input col min of D*inv_t, block partial sums --
__global__ __launch_bounds__(256) void k_pass2(float* __restrict__ ws) {
    __shared__ float xlds[64 * 149];
    __shared__ float red[256];
    int bx = blockIdx.x;
    int img = bx / 127;
    int tile = bx % 127;
    int i0t = tile * 64;
    int tid = threadIdx.x;
    int k = tid & 63, q = tid >> 6;

    {
        int i = i0t + k;
        bool valid = i < NP;
        int py = valid ? i / OW : 0;
        int px = valid ? (i - py * OW) : 0;
        const float* xbase = ws + WS_XR + img * IMG_STRIDE + py * HW + px;
        int e0 = q * 37, e1 = (q * 37 + 37 < DIM) ? q * 37 + 37 : DIM;
        for (int e = e0; e < e1; e++) {
            int c = e / 49;
            int rm = e - c * 49;
            int dy = rm / 7;
            int dx = rm - dy * 7;
            xlds[k * 149 + e] = valid ? xbase[c * CH_STRIDE + dy * HW + dx] : 0.0f;
        }
    }
    __syncthreads();

    int i = i0t + k;
    float x2i = ws[WS_N2X + img * NP + (i < NP ? i : 0)];
    const float* yim = ws + WS_YR + img * IMG_STRIDE;
    const float* n2y = ws + WS_N2Y + img * NP;
    const float* rinv = ws + WS_RINV + img * NP;
    const float* xl = &xlds[k * 149];

    float lmin = 3.4e38f;
    int t0q = q * 2025;
    int ty = t0q / OW, tx = t0q - (t0q / OW) * OW;
    for (int j = 0; j < 2025; j++) {
        const float* yb = yim + ty * HW + tx;
        float a0 = 0.f, a1 = 0.f, a2 = 0.f, a3 = 0.f;
#pragma unroll
        for (int c = 0; c < CH; c++) {
#pragma unroll
            for (int dy = 0; dy < PATCH; dy++) {
                const float* yr = yb + c * CH_STRIDE + dy * HW;
                const float* xr = xl + c * 49 + dy * 7;
                a0 = fmaf(xr[0], yr[0], a0);
                a1 = fmaf(xr[1], yr[1], a1);
                a2 = fmaf(xr[2], yr[2], a2);
                a3 = fmaf(xr[3], yr[3], a3);
                a0 = fmaf(xr[4], yr[4], a0);
                a1 = fmaf(xr[5], yr[5], a1);
                a2 = fmaf(xr[6], yr[6], a2);
            }
        }
        float cross = (a0 + a1) + (a2 + a3);
        float d = (n2y[t0q + j] + x2i - 2.0f * cross) * INV_D * rinv[t0q + j];
        lmin = fminf(lmin, d);
        tx++; if (tx == OW) { tx = 0; ty++; }
    }
    red[tid] = lmin;
    __syncthreads();
    if (tid < 64) {
        float m = fminf(fminf(red[tid], red[64 + tid]),
                        fminf(red[128 + tid], red[192 + tid]));
        red[tid] = (i0t + tid < NP) ? m : 0.0f;   // each slot read/written by one thread
    }
    __syncthreads();
    if (tid == 0) {
        float s = 0.0f;
        for (int u = 0; u < 64; u++) s += red[u];
        ws[WS_PART + img * 128 + tile] = s;
    }
}

// ---------------- finalize: mean over inputs, mean over batch ----
// Reference output is fp16 -> harness stores it as float32 (only bf16/int32
// get special read paths). Write a plain float.
__global__ void k_final(const float* __restrict__ ws, float* __restrict__ out) {
    if (threadIdx.x == 0 && blockIdx.x == 0) {
        float s0 = 0.0f, s1 = 0.0f;
        for (int u = 0; u < 127; u++) {
            s0 += ws[WS_PART + u];
            s1 += ws[WS_PART + 128 + u];
        }
        float m = 0.5f * (s0 * (1.0f / NP) + s1 * (1.0f / NP));
        out[0] = m;
    }
}

extern "C" void kernel_launch(void* const* d_in, const int* in_sizes, int n_in,
                              void* d_out, int out_size, void* d_ws, size_t ws_size,
                              hipStream_t stream) {
    const float* x = (const float*)d_in[0];
    const float* y = (const float*)d_in[1];
    float* ws = (float*)d_ws;
    float* out = (float*)d_out;

    k_prep<<<(IMGS * IMG_STRIDE + 255) / 256, 256, 0, stream>>>(x, y, ws);
    k_norms<<<(2 * IMGS * NP + 255) / 256, 256, 0, stream>>>(ws);
    k_pass1<<<IMGS * 127, 256, 0, stream>>>(ws);
    k_pass2<<<IMGS * 127, 256, 0, stream>>>(ws);
    k_final<<<1, 64, 0, stream>>>(ws, out);
}

// Round 3
// 291.830 us; speedup vs baseline: 16.9142x; 16.9142x over previous
//
#include <hip/hip_runtime.h>
#include <hip/hip_fp16.h>

// Problem constants
#define IMGS 2
#define OW 90
#define NP 8100                // 90*90 valid patches
#define HW 96
#define CH_STRIDE 9216
#define IMG_STRIDE 27648
#define KP 192                 // padded patch dim (147 -> 192 = 6*32)
#define MP 8192                // padded patch count
#define ALPHA 0.05f
#define INV_D (1.0f/147.0f)

typedef _Float16 half8 __attribute__((ext_vector_type(8)));
typedef float floatx4 __attribute__((ext_vector_type(4)));

// ws byte offsets
#define XP_OFF   0                              // fp16 [2][8192][192]
#define YP_OFF   (XP_OFF + IMGS*MP*KP*2)
#define N2X_OFF  (YP_OFF + IMGS*MP*KP*2)        // float [2][8192]
#define N2Y_OFF  (N2X_OFF + IMGS*MP*4)
#define RMIN_OFF (N2Y_OFF + IMGS*MP*4)          // int-bits float [2][8192]
#define RINV_OFF (RMIN_OFF + IMGS*MP*4)
#define CMIN_OFF (RINV_OFF + IMGS*MP*4)

// -------- build fp16 patch matrices (reference casts to fp16 BEFORE patches)
// one thread per (tensor,img,row,16B-chunk); vectorized 16B stores
__global__ __launch_bounds__(256) void k_build(const float* __restrict__ x,
                                               const float* __restrict__ y,
                                               char* __restrict__ wsb) {
    int gid = blockIdx.x * 256 + threadIdx.x;      // 2*2*8192*24 total
    int chunk = gid % 24;
    int row = (gid / 24) & (MP - 1);
    int rest = gid / (24 * MP);
    int img = rest & 1;
    int tensor = rest >> 1;
    const float* src = (tensor ? y : x) + img * IMG_STRIDE;
    _Float16* dst = (_Float16*)(wsb + (tensor ? YP_OFF : XP_OFF)) +
                    ((size_t)img * MP + row) * KP + chunk * 8;
    int py = row / OW, px = row - py * OW;
    bool rvalid = row < NP;
    half8 v;
#pragma unroll
    for (int j = 0; j < 8; j++) {
        int k = chunk * 8 + j;
        float f = 0.0f;
        if (rvalid && k < 147) {
            int c = k / 49;
            int rm = k - c * 49;
            int dy = rm / 7, dx = rm - dy * 7;
            f = src[c * CH_STRIDE + (py + dy) * HW + px + dx];
        }
        v[j] = (_Float16)f;
    }
    *(half8*)dst = v;
}

// -------- squared norms from the fp16 matrices (fp32 accumulate) --------
__global__ __launch_bounds__(256) void k_norms(char* __restrict__ wsb) {
    int gid = blockIdx.x * 256 + threadIdx.x;      // 2*2*8192
    int row = gid & (MP - 1);
    int img = (gid >> 13) & 1;
    int tensor = gid >> 14;
    const _Float16* p = (const _Float16*)(wsb + (tensor ? YP_OFF : XP_OFF)) +
                        ((size_t)img * MP + row) * KP;
    float s = 0.0f;
    for (int k = 0; k < KP; k += 8) {
        half8 h = *(const half8*)(p + k);
#pragma unroll
        for (int j = 0; j < 8; j++) {
            float f = (float)h[j];
            s = fmaf(f, f, s);
        }
    }
    ((float*)(wsb + (tensor ? N2Y_OFF : N2X_OFF)))[img * MP + row] = s;
}

// -------- init min arrays to +inf bits (ws is re-poisoned every call) -----
__global__ __launch_bounds__(256) void k_init(char* __restrict__ wsb) {
    int gid = blockIdx.x * 256 + threadIdx.x;      // 2 * 2*8192
    if (gid < IMGS * MP)
        ((int*)(wsb + RMIN_OFF))[gid] = 0x7f800000;
    else
        ((int*)(wsb + CMIN_OFF))[gid - IMGS * MP] = 0x7f800000;
}

// -------- fused GEMM + distance + min reduction ---------------------------
// PASS 1: row (target) min of d -> global rowmin
// PASS 2: col (input) min of d*rinv[row] -> global colmin
template <int PASS>
__global__ __launch_bounds__(256, 3) void k_gemm(char* __restrict__ wsb) {
    __shared__ _Float16 As[128 * 72];   // stride 72 halfs = 144B -> 2-way bank alias (free)
    __shared__ _Float16 Bs[128 * 72];
    int tid = threadIdx.x;
    int lane = tid & 63, w = tid >> 6;
    int wm = (w >> 1) * 64, wn = (w & 1) * 64;
    int quad = lane >> 4, col16 = lane & 15;
    int ntile = blockIdx.x, mtile = blockIdx.y, img = blockIdx.z;

    const _Float16* Amat = (const _Float16*)(wsb + YP_OFF) +
                           ((size_t)img * MP + mtile * 128) * KP;   // targets = rows
    const _Float16* Bmat = (const _Float16*)(wsb + XP_OFF) +
                           ((size_t)img * MP + ntile * 128) * KP;   // inputs = cols

    floatx4 acc[4][4];
#pragma unroll
    for (int i = 0; i < 4; i++)
#pragma unroll
        for (int j = 0; j < 4; j++) acc[i][j] = (floatx4){0.f, 0.f, 0.f, 0.f};

    for (int c = 0; c < 3; c++) {                   // K chunks of 64
        __syncthreads();
#pragma unroll
        for (int r = 0; r < 4; r++) {               // stage 128 rows x 64 halfs, both mats
            int id = tid + r * 256;
            int row = id >> 3, off = id & 7;
            *(uint4*)(&As[row * 72 + off * 8]) =
                *(const uint4*)(Amat + (size_t)row * KP + c * 64 + off * 8);
            *(uint4*)(&Bs[row * 72 + off * 8]) =
                *(const uint4*)(Bmat + (size_t)row * KP + c * 64 + off * 8);
        }
        __syncthreads();
#pragma unroll
        for (int ks = 0; ks < 2; ks++) {
            half8 a[4], b[4];
#pragma unroll
            for (int mi = 0; mi < 4; mi++)
                a[mi] = *(const half8*)(&As[(wm + mi * 16 + col16) * 72 + ks * 32 + quad * 8]);
#pragma unroll
            for (int ni = 0; ni < 4; ni++)
                b[ni] = *(const half8*)(&Bs[(wn + ni * 16 + col16) * 72 + ks * 32 + quad * 8]);
#pragma unroll
            for (int mi = 0; mi < 4; mi++)
#pragma unroll
                for (int ni = 0; ni < 4; ni++)
                    acc[mi][ni] = __builtin_amdgcn_mfma_f32_16x16x32_f16(
                        a[mi], b[ni], acc[mi][ni], 0, 0, 0);
        }
    }
    __syncthreads();

    // epilogue scratch (reuse As)
    int* redmin = (int*)As;
    float* y2s = (float*)As + 128;
    float* x2s = (float*)As + 256;
    float* rvs = (float*)As + 384;
    if (tid < 128) {
        redmin[tid] = 0x7f800000;
        y2s[tid] = ((const float*)(wsb + N2Y_OFF))[img * MP + mtile * 128 + tid];
        x2s[tid] = ((const float*)(wsb + N2X_OFF))[img * MP + ntile * 128 + tid];
        if (PASS == 2) {
            int grow = mtile * 128 + tid;
            rvs[tid] = (grow < NP) ? ((const float*)(wsb + RINV_OFF))[img * MP + grow]
                                   : -1.0f;   // marker: masked (padded) row
        }
    }
    __syncthreads();

    // C/D layout (16x16x32): col = lane&15, row = (lane>>4)*4 + reg
    if (PASS == 1) {
#pragma unroll
        for (int mi = 0; mi < 4; mi++)
#pragma unroll
            for (int r = 0; r < 4; r++) {
                int row_l = wm + mi * 16 + quad * 4 + r;
                float y2v = y2s[row_l];
                float best = 1e30f;
#pragma unroll
                for (int ni = 0; ni < 4; ni++) {
                    int col_l = wn + ni * 16 + col16;
                    float d = fmaf(-2.0f, acc[mi][ni][r], y2v + x2s[col_l]) * INV_D;
                    if (ntile * 128 + col_l < NP) best = fminf(best, d);  // mask pad cols
                }
                best = fminf(best, __shfl_xor(best, 1, 16));
                best = fminf(best, __shfl_xor(best, 2, 16));
                best = fminf(best, __shfl_xor(best, 4, 16));
                best = fminf(best, __shfl_xor(best, 8, 16));
                if (col16 == 0) atomicMin(&redmin[row_l], __float_as_int(best));
            }
        __syncthreads();
        if (tid < 128)
            atomicMin((int*)(wsb + RMIN_OFF) + img * MP + mtile * 128 + tid, redmin[tid]);
    } else {
#pragma unroll
        for (int ni = 0; ni < 4; ni++) {
            int col_l = wn + ni * 16 + col16;
            float x2v = x2s[col_l];
            float best = 1e30f;
#pragma unroll
            for (int mi = 0; mi < 4; mi++)
#pragma unroll
                for (int r = 0; r < 4; r++) {
                    int row_l = wm + mi * 16 + quad * 4 + r;
                    float rv = rvs[row_l];
                    float d = fmaf(-2.0f, acc[mi][ni][r], y2s[row_l] + x2v) * INV_D * rv;
                    if (rv > 0.0f) best = fminf(best, d);   // mask pad rows
                }
            best = fminf(best, __shfl_xor(best, 16, 64));
            best = fminf(best, __shfl_xor(best, 32, 64));
            if (quad == 0) atomicMin(&redmin[col_l], __float_as_int(best));
        }
        __syncthreads();
        if (tid < 128)
            atomicMin((int*)(wsb + CMIN_OFF) + img * MP + ntile * 128 + tid, redmin[tid]);
    }
}

// -------- rinv = 1/(rowmin + alpha) ---------------------------------------
__global__ __launch_bounds__(256) void k_rinv(char* __restrict__ wsb) {
    int gid = blockIdx.x * 256 + threadIdx.x;      // 2*8192
    float rm = __int_as_float(((const int*)(wsb + RMIN_OFF))[gid]);
    ((float*)(wsb + RINV_OFF))[gid] = 1.0f / (rm + ALPHA);
}

// -------- finalize: mean over inputs, mean over images; fp16 ref -> f32 out
__global__ __launch_bounds__(256) void k_final(const char* __restrict__ wsb,
                                               float* __restrict__ out) {
    __shared__ float red[256];
    int tid = threadIdx.x;
    const int* cm = (const int*)(wsb + CMIN_OFF);
    float s = 0.0f;
    for (int i = tid; i < NP; i += 256) {
        s += __int_as_float(cm[i]);
        s += __int_as_float(cm[MP + i]);
    }
    red[tid] = s;
    __syncthreads();
    for (int st = 128; st > 0; st >>= 1) {
        if (tid < st) red[tid] += red[tid + st];
        __syncthreads();
    }
    if (tid == 0) out[0] = red[0] * (0.5f / NP);
}

extern "C" void kernel_launch(void* const* d_in, const int* in_sizes, int n_in,
                              void* d_out, int out_size, void* d_ws, size_t ws_size,
                              hipStream_t stream) {
    const float* x = (const float*)d_in[0];
    const float* y = (const float*)d_in[1];
    char* wsb = (char*)d_ws;
    float* out = (float*)d_out;

    k_build<<<(2 * IMGS * MP * 24) / 256, 256, 0, stream>>>(x, y, wsb);
    k_norms<<<(2 * IMGS * MP) / 256, 256, 0, stream>>>(wsb);
    k_init<<<(2 * IMGS * MP) / 256, 256, 0, stream>>>(wsb);
    k_gemm<1><<<dim3(64, 64, IMGS), 256, 0, stream>>>(wsb);
    k_rinv<<<(IMGS * MP) / 256, 256, 0, stream>>>(wsb);
    k_gemm<2><<<dim3(64, 64, IMGS), 256, 0, stream>>>(wsb);
    k_final<<<1, 256, 0, stream>>>(wsb, out);
}

// Round 4
// 230.702 us; speedup vs baseline: 21.3959x; 1.2650x over previous
//
#include <hip/hip_runtime.h>
#include <hip/hip_fp16.h>

// Problem constants
#define IMGS 2
#define OW 90
#define NP 8100                // 90*90 valid patches
#define HW 96
#define CH_STRIDE 9216
#define IMG_STRIDE 27648
#define KP 192                 // padded patch dim (147 -> 192); halfs 147..191 are ZERO
#define MP 8192                // padded patch count
#define ALPHA 0.05f
#define INV_D (1.0f/147.0f)

typedef _Float16 half8 __attribute__((ext_vector_type(8)));
typedef float floatx4 __attribute__((ext_vector_type(4)));

// async global->LDS, 16B per lane; LDS dest = uniform base + lane*16
#define GLD_LDS16(gp, lp)                                                     \
    __builtin_amdgcn_global_load_lds(                                         \
        (const __attribute__((address_space(1))) void*)(gp),                  \
        (__attribute__((address_space(3))) void*)(lp), 16, 0, 0)

// ws byte offsets
#define XP_OFF   0                              // fp16 [2][8192][192]
#define YP_OFF   (XP_OFF + IMGS*MP*KP*2)
#define N2X_OFF  (YP_OFF + IMGS*MP*KP*2)        // float [2][8192]
#define N2Y_OFF  (N2X_OFF + IMGS*MP*4)
#define RMIN_OFF (N2Y_OFF + IMGS*MP*4)          // int-bits float [2][8192]
#define RINV_OFF (RMIN_OFF + IMGS*MP*4)
#define CMIN_OFF (RINV_OFF + IMGS*MP*4)

// -------- build fp16 patch matrices (reference casts to fp16 BEFORE patches)
__global__ __launch_bounds__(256) void k_build(const float* __restrict__ x,
                                               const float* __restrict__ y,
                                               char* __restrict__ wsb) {
    int gid = blockIdx.x * 256 + threadIdx.x;      // 2*2*8192*24 total
    int chunk = gid % 24;
    int row = (gid / 24) & (MP - 1);
    int rest = gid / (24 * MP);
    int img = rest & 1;
    int tensor = rest >> 1;
    const float* src = (tensor ? y : x) + img * IMG_STRIDE;
    _Float16* dst = (_Float16*)(wsb + (tensor ? YP_OFF : XP_OFF)) +
                    ((size_t)img * MP + row) * KP + chunk * 8;
    int py = row / OW, px = row - py * OW;
    bool rvalid = row < NP;
    half8 v;
#pragma unroll
    for (int j = 0; j < 8; j++) {
        int k = chunk * 8 + j;
        float f = 0.0f;
        if (rvalid && k < 147) {
            int c = k / 49;
            int rm = k - c * 49;
            int dy = rm / 7, dx = rm - dy * 7;
            f = src[c * CH_STRIDE + (py + dy) * HW + px + dx];
        }
        v[j] = (_Float16)f;
    }
    *(half8*)dst = v;
}

// -------- squared norms from the fp16 matrices (fp32 accumulate) --------
__global__ __launch_bounds__(256) void k_norms(char* __restrict__ wsb) {
    int gid = blockIdx.x * 256 + threadIdx.x;      // 2*2*8192
    int row = gid & (MP - 1);
    int img = (gid >> 13) & 1;
    int tensor = gid >> 14;
    const _Float16* p = (const _Float16*)(wsb + (tensor ? YP_OFF : XP_OFF)) +
                        ((size_t)img * MP + row) * KP;
    float s = 0.0f;
    for (int k = 0; k < KP; k += 8) {
        half8 h = *(const half8*)(p + k);
#pragma unroll
        for (int j = 0; j < 8; j++) {
            float f = (float)h[j];
            s = fmaf(f, f, s);
        }
    }
    ((float*)(wsb + (tensor ? N2Y_OFF : N2X_OFF)))[img * MP + row] = s;
}

// -------- init min arrays to +inf bits (ws is re-poisoned every call) -----
__global__ __launch_bounds__(256) void k_init(char* __restrict__ wsb) {
    int gid = blockIdx.x * 256 + threadIdx.x;      // 2 * 2*8192
    if (gid < IMGS * MP)
        ((int*)(wsb + RMIN_OFF))[gid] = 0x7f800000;
    else
        ((int*)(wsb + CMIN_OFF))[gid - IMGS * MP] = 0x7f800000;
}

// -------- fused GEMM + distance + min reduction ---------------------------
// 128x128 tile, 4 waves, 4x4 16x16x32 f16 fragments per wave.
// LDS: unpadded 64-half rows (128B = 8 x 16B chunks), XOR-swizzled
// (slot = chunk ^ (row&7)) applied on the GLOBAL address side so
// global_load_lds's lane-contiguous LDS deposit yields the swizzled layout.
// Fragment reads: quad-group of 16 lanes hits all 8 bank-groups twice -> free.
// K: halfs 160..191 are all zero -> skip the last K-step (exact).
template <int PASS>
__global__ __launch_bounds__(256, 3) void k_gemm(char* __restrict__ wsb) {
    __shared__ __align__(16) _Float16 As[128 * 64];
    __shared__ __align__(16) _Float16 Bs[128 * 64];
    int tid = threadIdx.x;
    int lane = tid & 63, w = tid >> 6;
    int wm = (w >> 1) * 64, wn = (w & 1) * 64;
    int quad = lane >> 4, col16 = lane & 15;
    int ntile = blockIdx.x, mtile = blockIdx.y, img = blockIdx.z;

    const _Float16* Amat = (const _Float16*)(wsb + YP_OFF) +
                           ((size_t)img * MP + mtile * 128) * KP;   // targets = rows
    const _Float16* Bmat = (const _Float16*)(wsb + XP_OFF) +
                           ((size_t)img * MP + ntile * 128) * KP;   // inputs = cols

    // staging addresses (per-lane constant across chunks)
    int rl = lane >> 3;                       // row within 8-row group
    int cg = (lane & 7) ^ rl;                 // swizzled global chunk
    floatx4 acc[4][4];
#pragma unroll
    for (int i = 0; i < 4; i++)
#pragma unroll
        for (int j = 0; j < 4; j++) acc[i][j] = (floatx4){0.f, 0.f, 0.f, 0.f};

#pragma unroll
    for (int c = 0; c < 3; c++) {             // K chunks of 64 halfs
        if (c) __syncthreads();               // previous compute done before overwrite
#pragma unroll
        for (int i = 0; i < 4; i++) {
            int rowgrp = (i * 4 + w) * 8;     // wave-uniform
            const _Float16* ga = Amat + (size_t)(rowgrp + rl) * KP + c * 64 + cg * 8;
            const _Float16* gb = Bmat + (size_t)(rowgrp + rl) * KP + c * 64 + cg * 8;
            GLD_LDS16(ga, &As[rowgrp * 64]);
            GLD_LDS16(gb, &Bs[rowgrp * 64]);
        }
        __syncthreads();                      // drains vmcnt (global_load_lds) too
        int ksmax = (c == 2) ? 1 : 2;         // chunk2 ks=1 covers halfs 160..191 == 0
#pragma unroll
        for (int ks = 0; ks < 2; ks++) {
            if (ks >= ksmax) break;
            half8 a[4], b[4];
#pragma unroll
            for (int mi = 0; mi < 4; mi++) {
                int row = wm + mi * 16 + col16;
                a[mi] = *(const half8*)(&As[row * 64 + (((ks * 4 + quad) ^ (col16 & 7)) * 8)]);
            }
#pragma unroll
            for (int ni = 0; ni < 4; ni++) {
                int row = wn + ni * 16 + col16;
                b[ni] = *(const half8*)(&Bs[row * 64 + (((ks * 4 + quad) ^ (col16 & 7)) * 8)]);
            }
#pragma unroll
            for (int mi = 0; mi < 4; mi++)
#pragma unroll
                for (int ni = 0; ni < 4; ni++)
                    acc[mi][ni] = __builtin_amdgcn_mfma_f32_16x16x32_f16(
                        a[mi], b[ni], acc[mi][ni], 0, 0, 0);
        }
    }
    __syncthreads();

    // epilogue scratch (reuse As)
    int* redmin = (int*)As;
    float* y2s = (float*)As + 128;
    float* x2s = (float*)As + 256;
    float* rvs = (float*)As + 384;
    if (tid < 128) {
        redmin[tid] = 0x7f800000;
        y2s[tid] = ((const float*)(wsb + N2Y_OFF))[img * MP + mtile * 128 + tid];
        x2s[tid] = ((const float*)(wsb + N2X_OFF))[img * MP + ntile * 128 + tid];
        if (PASS == 2) {
            int grow = mtile * 128 + tid;
            rvs[tid] = (grow < NP) ? ((const float*)(wsb + RINV_OFF))[img * MP + grow]
                                   : -1.0f;   // marker: masked (padded) row
        }
    }
    __syncthreads();

    // C/D layout (16x16x32): col = lane&15, row = (lane>>4)*4 + reg
    if (PASS == 1) {
#pragma unroll
        for (int mi = 0; mi < 4; mi++)
#pragma unroll
            for (int r = 0; r < 4; r++) {
                int row_l = wm + mi * 16 + quad * 4 + r;
                float y2v = y2s[row_l];
                float best = 1e30f;
#pragma unroll
                for (int ni = 0; ni < 4; ni++) {
                    int col_l = wn + ni * 16 + col16;
                    float d = fmaf(-2.0f, acc[mi][ni][r], y2v + x2s[col_l]) * INV_D;
                    if (ntile * 128 + col_l < NP) best = fminf(best, d);  // mask pad cols
                }
                best = fminf(best, __shfl_xor(best, 1, 16));
                best = fminf(best, __shfl_xor(best, 2, 16));
                best = fminf(best, __shfl_xor(best, 4, 16));
                best = fminf(best, __shfl_xor(best, 8, 16));
                if (col16 == 0) atomicMin(&redmin[row_l], __float_as_int(best));
            }
        __syncthreads();
        if (tid < 128)
            atomicMin((int*)(wsb + RMIN_OFF) + img * MP + mtile * 128 + tid, redmin[tid]);
    } else {
#pragma unroll
        for (int ni = 0; ni < 4; ni++) {
            int col_l = wn + ni * 16 + col16;
            float x2v = x2s[col_l];
            float best = 1e30f;
#pragma unroll
            for (int mi = 0; mi < 4; mi++)
#pragma unroll
                for (int r = 0; r < 4; r++) {
                    int row_l = wm + mi * 16 + quad * 4 + r;
                    float rv = rvs[row_l];
                    float d = fmaf(-2.0f, acc[mi][ni][r], y2s[row_l] + x2v) * INV_D * rv;
                    if (rv > 0.0f) best = fminf(best, d);   // mask pad rows
                }
            best = fminf(best, __shfl_xor(best, 16, 64));
            best = fminf(best, __shfl_xor(best, 32, 64));
            if (quad == 0) atomicMin(&redmin[col_l], __float_as_int(best));
        }
        __syncthreads();
        if (tid < 128)
            atomicMin((int*)(wsb + CMIN_OFF) + img * MP + ntile * 128 + tid, redmin[tid]);
    }
}

// -------- rinv = 1/(rowmin + alpha) ---------------------------------------
__global__ __launch_bounds__(256) void k_rinv(char* __restrict__ wsb) {
    int gid = blockIdx.x * 256 + threadIdx.x;      // 2*8192
    float rm = __int_as_float(((const int*)(wsb + RMIN_OFF))[gid]);
    ((float*)(wsb + RINV_OFF))[gid] = 1.0f / (rm + ALPHA);
}

// -------- finalize: mean over inputs, mean over images; fp16 ref -> f32 out
__global__ __launch_bounds__(256) void k_final(const char* __restrict__ wsb,
                                               float* __restrict__ out) {
    __shared__ float red[256];
    int tid = threadIdx.x;
    const int* cm = (const int*)(wsb + CMIN_OFF);
    float s = 0.0f;
    for (int i = tid; i < NP; i += 256) {
        s += __int_as_float(cm[i]);
        s += __int_as_float(cm[MP + i]);
    }
    red[tid] = s;
    __syncthreads();
    for (int st = 128; st > 0; st >>= 1) {
        if (tid < st) red[tid] += red[tid + st];
        __syncthreads();
    }
    if (tid == 0) out[0] = red[0] * (0.5f / NP);
}

extern "C" void kernel_launch(void* const* d_in, const int* in_sizes, int n_in,
                              void* d_out, int out_size, void* d_ws, size_t ws_size,
                              hipStream_t stream) {
    const float* x = (const float*)d_in[0];
    const float* y = (const float*)d_in[1];
    char* wsb = (char*)d_ws;
    float* out = (float*)d_out;

    k_build<<<(2 * IMGS * MP * 24) / 256, 256, 0, stream>>>(x, y, wsb);
    k_norms<<<(2 * IMGS * MP) / 256, 256, 0, stream>>>(wsb);
    k_init<<<(2 * IMGS * MP) / 256, 256, 0, stream>>>(wsb);
    k_gemm<1><<<dim3(64, 64, IMGS), 256, 0, stream>>>(wsb);
    k_rinv<<<(IMGS * MP) / 256, 256, 0, stream>>>(wsb);
    k_gemm<2><<<dim3(64, 64, IMGS), 256, 0, stream>>>(wsb);
    k_final<<<1, 256, 0, stream>>>(wsb, out);
}

// Round 5
// 196.543 us; speedup vs baseline: 25.1145x; 1.1738x over previous
//
#include <hip/hip_runtime.h>
#include <hip/hip_fp16.h>

// Problem constants
#define IMGS 2
#define OW 90
#define NP 8100                // 90*90 valid patches
#define HW 96
#define CH_STRIDE 9216
#define IMG_STRIDE 27648
#define KP 192                 // padded row stride in halfs
#define MP 8192                // padded patch count
#define ALPHA 0.05f
#define INV_D (1.0f/147.0f)
#define PAD_SENTINEL 60000.0f  // finite fp16 value >> any real (x2-2c) magnitude

typedef _Float16 half8 __attribute__((ext_vector_type(8)));
typedef float floatx4 __attribute__((ext_vector_type(4)));

// async global->LDS, 16B per lane; LDS dest = uniform base + lane*16
#define GLD_LDS16(gp, lp)                                                     \
    __builtin_amdgcn_global_load_lds(                                         \
        (const __attribute__((address_space(1))) void*)(gp),                  \
        (__attribute__((address_space(3))) void*)(lp), 16, 0, 0)

// ws byte offsets
// A matrix = -2*Y with slot147 = 1.0      (fp16 [2][8192][192])
// B matrix =    X with slot147 = x2_i (valid) / 60000 (pad row)
#define XP_OFF   0
#define YP_OFF   (XP_OFF + IMGS*MP*KP*2)
#define N2Y_OFF  (YP_OFF + IMGS*MP*KP*2)        // float [2][8192] (y norms)
#define RMIN_OFF (N2Y_OFF + IMGS*MP*4)          // int-bits float [2][8192]
#define RINV_OFF (RMIN_OFF + IMGS*MP*4)         // r' = INV_D * rinv  (0 for pad rows)
#define AY_OFF   (RINV_OFF + IMGS*MP*4)         // ay = r' * y2       (+inf for pad rows)
#define CMIN_OFF (AY_OFF + IMGS*MP*4)

// -------- fused build + norms + min-init ----------------------------------
// one row per 32 lanes (lane j handles halfs 8j..8j+7); 8 rows per 256-block
__global__ __launch_bounds__(256) void k_build(const float* __restrict__ x,
                                               const float* __restrict__ y,
                                               char* __restrict__ wsb) {
    int tid = threadIdx.x;
    int hwv = tid >> 5;                      // half-wave 0..7
    int l = tid & 31;
    int grow = blockIdx.x * 8 + hwv;         // 0..32767
    int tensor = grow >> 14;                 // 0 = x(B), 1 = y(A)
    int img = (grow >> 13) & 1;
    int row = grow & (MP - 1);
    const float* src = (tensor ? y : x) + img * IMG_STRIDE;
    int py = row / OW, px = row - py * OW;
    bool rvalid = row < NP;

    float vals[8];
    float ss = 0.0f;
#pragma unroll
    for (int j = 0; j < 8; j++) {
        int k = l * 8 + j;
        float v = 0.0f;
        if (rvalid && k < 147) {
            int c = k / 49;
            int rm = k - c * 49;
            int dy = rm / 7, dx = rm - dy * 7;
            v = src[c * CH_STRIDE + (py + dy) * HW + px + dx];
        }
        vals[j] = v;
        ss = fmaf(v, v, ss);
    }
    // norm reduce across the 32 lanes of this row
#pragma unroll
    for (int m = 1; m < 32; m <<= 1) ss += __shfl_xor(ss, m, 32);
    // ss is the fp32 norm of the fp16-rounded... NOTE: vals are fp32 originals;
    // round to fp16 first for exact parity with the fp16 patch values:
    // recompute ss from fp16-rounded values
    float ss16 = 0.0f;
#pragma unroll
    for (int j = 0; j < 8; j++) {
        float v = (float)(_Float16)vals[j];
        vals[j] = v;
        ss16 = fmaf(v, v, ss16);
    }
#pragma unroll
    for (int m = 1; m < 32; m <<= 1) ss16 += __shfl_xor(ss16, m, 32);

    if (tensor && l == 0)
        ((float*)(wsb + N2Y_OFF))[img * MP + row] = rvalid ? ss16 : 0.0f;

    half8 h;
#pragma unroll
    for (int j = 0; j < 8; j++) {
        float f = vals[j];
        if (tensor) f *= -2.0f;              // A = -2*Y (exact in fp16)
        h[j] = (_Float16)f;
    }
    if (l == 18) {                           // k = 147 is j=3 of chunk 18
        h[3] = tensor ? (_Float16)1.0f
                      : (rvalid ? (_Float16)ss16 : (_Float16)PAD_SENTINEL);
    }
    if (l < 24) {
        _Float16* dst = (_Float16*)(wsb + (tensor ? YP_OFF : XP_OFF)) +
                        ((size_t)img * MP + row) * KP + l * 8;
        *(half8*)dst = h;
    }
    // min-array init: 32768 ints across 4096 blocks
    if (tid < 8) {
        int gi = blockIdx.x * 8 + tid;
        if (gi < IMGS * MP)
            ((int*)(wsb + RMIN_OFF))[gi] = 0x7f800000;
        else
            ((int*)(wsb + CMIN_OFF))[gi - IMGS * MP] = 0x7f800000;
    }
}

// -------- fused GEMM + min reduction --------------------------------------
// acc = x2_i - 2*cross(t,i) directly from MFMA (norm baked into K slot 147).
// PASS 1: rowmin_t = min_i acc                 -> global RMIN (raw)
// PASS 2: colmin_i = min_t (r'_t*acc + ay_t)   -> global CMIN
template <int PASS>
__global__ __launch_bounds__(256, 3) void k_gemm(char* __restrict__ wsb) {
    __shared__ __align__(16) _Float16 As[128 * 64];
    __shared__ __align__(16) _Float16 Bs[128 * 64];
    int tid = threadIdx.x;
    int lane = tid & 63, w = tid >> 6;
    int wm = (w >> 1) * 64, wn = (w & 1) * 64;
    int quad = lane >> 4, col16 = lane & 15;
    int ntile = blockIdx.x, mtile = blockIdx.y, img = blockIdx.z;

    const _Float16* Amat = (const _Float16*)(wsb + YP_OFF) +
                           ((size_t)img * MP + mtile * 128) * KP;   // -2*Y rows
    const _Float16* Bmat = (const _Float16*)(wsb + XP_OFF) +
                           ((size_t)img * MP + ntile * 128) * KP;   // X rows

    int rl = lane >> 3;                       // row within 8-row group
    int cg = (lane & 7) ^ rl;                 // swizzled global chunk
    floatx4 acc[4][4];
#pragma unroll
    for (int i = 0; i < 4; i++)
#pragma unroll
        for (int j = 0; j < 4; j++) acc[i][j] = (floatx4){0.f, 0.f, 0.f, 0.f};

#pragma unroll
    for (int c = 0; c < 3; c++) {             // K chunks of 64 halfs
        if (c) __syncthreads();
#pragma unroll
        for (int i = 0; i < 4; i++) {
            int rowgrp = (i * 4 + w) * 8;     // wave-uniform
            const _Float16* ga = Amat + (size_t)(rowgrp + rl) * KP + c * 64 + cg * 8;
            const _Float16* gb = Bmat + (size_t)(rowgrp + rl) * KP + c * 64 + cg * 8;
            GLD_LDS16(ga, &As[rowgrp * 64]);
            GLD_LDS16(gb, &Bs[rowgrp * 64]);
        }
        __syncthreads();
        int ksmax = (c == 2) ? 1 : 2;         // halfs 160..191 are zero -> skip
#pragma unroll
        for (int ks = 0; ks < 2; ks++) {
            if (ks >= ksmax) break;
            half8 a[4], b[4];
#pragma unroll
            for (int mi = 0; mi < 4; mi++) {
                int row = wm + mi * 16 + col16;
                a[mi] = *(const half8*)(&As[row * 64 + (((ks * 4 + quad) ^ (col16 & 7)) * 8)]);
            }
#pragma unroll
            for (int ni = 0; ni < 4; ni++) {
                int row = wn + ni * 16 + col16;
                b[ni] = *(const half8*)(&Bs[row * 64 + (((ks * 4 + quad) ^ (col16 & 7)) * 8)]);
            }
#pragma unroll
            for (int mi = 0; mi < 4; mi++)
#pragma unroll
                for (int ni = 0; ni < 4; ni++)
                    acc[mi][ni] = __builtin_amdgcn_mfma_f32_16x16x32_f16(
                        a[mi], b[ni], acc[mi][ni], 0, 0, 0);
        }
    }
    __syncthreads();

    if (PASS == 1) {
        int* redmin = (int*)As;
        if (tid < 128) redmin[tid] = 0x7f800000;
        __syncthreads();
        // C/D layout: col = lane&15, row = quad*4 + reg
#pragma unroll
        for (int mi = 0; mi < 4; mi++)
#pragma unroll
            for (int r = 0; r < 4; r++) {
                int row_l = wm + mi * 16 + quad * 4 + r;
                float best = fminf(fminf(acc[mi][0][r], acc[mi][1][r]),
                                   fminf(acc[mi][2][r], acc[mi][3][r]));
                best = fminf(best, __shfl_xor(best, 1, 16));
                best = fminf(best, __shfl_xor(best, 2, 16));
                best = fminf(best, __shfl_xor(best, 4, 16));
                best = fminf(best, __shfl_xor(best, 8, 16));
                if (col16 == 0) atomicMin(&redmin[row_l], __float_as_int(best));
            }
        __syncthreads();
        if (tid < 128)
            atomicMin((int*)(wsb + RMIN_OFF) + img * MP + mtile * 128 + tid, redmin[tid]);
    } else {
        float* rs = (float*)As;          // r' per row
        float* ay = (float*)As + 128;    // ay per row
        int* colmin = (int*)As + 256;
        if (tid < 128) {
            rs[tid] = ((const float*)(wsb + RINV_OFF))[img * MP + mtile * 128 + tid];
            ay[tid] = ((const float*)(wsb + AY_OFF))[img * MP + mtile * 128 + tid];
            colmin[tid] = 0x7f800000;
        }
        __syncthreads();
        float bestni[4] = {1e30f, 1e30f, 1e30f, 1e30f};
#pragma unroll
        for (int mi = 0; mi < 4; mi++)
#pragma unroll
            for (int r = 0; r < 4; r++) {
                int row_l = wm + mi * 16 + quad * 4 + r;
                float rr = rs[row_l];    // broadcast (same addr across quad-group)
                float aa = ay[row_l];
#pragma unroll
                for (int ni = 0; ni < 4; ni++)
                    bestni[ni] = fminf(bestni[ni], fmaf(rr, acc[mi][ni][r], aa));
            }
#pragma unroll
        for (int ni = 0; ni < 4; ni++) {
            float best = bestni[ni];
            best = fminf(best, __shfl_xor(best, 16, 64));
            best = fminf(best, __shfl_xor(best, 32, 64));
            if (quad == 0)
                atomicMin(&colmin[wn + ni * 16 + col16], __float_as_int(best));
        }
        __syncthreads();
        if (tid < 128)
            atomicMin((int*)(wsb + CMIN_OFF) + img * MP + ntile * 128 + tid, colmin[tid]);
    }
}

// -------- rinv: finish rowmin, bake constants for pass 2 ------------------
__global__ __launch_bounds__(256) void k_rinv(char* __restrict__ wsb) {
    int gid = blockIdx.x * 256 + threadIdx.x;      // 2*8192
    float rm = __int_as_float(((const int*)(wsb + RMIN_OFF))[gid]);
    float y2 = ((const float*)(wsb + N2Y_OFF))[gid];
    float d = (y2 + rm) * INV_D;                   // rowmin distance
    float rp = INV_D / (d + ALPHA);                // r' = INV_D * rinv
    bool valid = (gid & (MP - 1)) < NP;
    ((float*)(wsb + RINV_OFF))[gid] = valid ? rp : 0.0f;
    ((float*)(wsb + AY_OFF))[gid] = valid ? rp * y2 : __builtin_huge_valf();
}

// -------- finalize: mean over inputs, mean over images --------------------
__global__ __launch_bounds__(256) void k_final(const char* __restrict__ wsb,
                                               float* __restrict__ out) {
    __shared__ float red[256];
    int tid = threadIdx.x;
    const int* cm = (const int*)(wsb + CMIN_OFF);
    float s = 0.0f;
    for (int i = tid; i < NP; i += 256) {
        s += __int_as_float(cm[i]);
        s += __int_as_float(cm[MP + i]);
    }
    red[tid] = s;
    __syncthreads();
    for (int st = 128; st > 0; st >>= 1) {
        if (tid < st) red[tid] += red[tid + st];
        __syncthreads();
    }
    if (tid == 0) out[0] = red[0] * (0.5f / NP);
}

extern "C" void kernel_launch(void* const* d_in, const int* in_sizes, int n_in,
                              void* d_out, int out_size, void* d_ws, size_t ws_size,
                              hipStream_t stream) {
    const float* x = (const float*)d_in[0];
    const float* y = (const float*)d_in[1];
    char* wsb = (char*)d_ws;
    float* out = (float*)d_out;

    k_build<<<4096, 256, 0, stream>>>(x, y, wsb);
    k_gemm<1><<<dim3(64, 64, IMGS), 256, 0, stream>>>(wsb);
    k_rinv<<<(IMGS * MP) / 256, 256, 0, stream>>>(wsb);
    k_gemm<2><<<dim3(64, 64, IMGS), 256, 0, stream>>>(wsb);
    k_final<<<1, 256, 0, stream>>>(wsb, out);
}